// Round 13
// baseline (3127.083 us; speedup 1.0000x reference)
//
#include <hip/hip_runtime.h>
#include <hip/hip_bf16.h>
#include <math.h>

#define BQ   512
#define EDIM 512
#define HDIM 1024
#define VDIM 1024
#define TLEN 32
#define TOUT 33
#define PGS  (BQ * 4 * HDIM)   // gate partial plane stride
#define PLS  (BQ * VDIM)       // logits partial plane stride

typedef _Float16 half8  __attribute__((ext_vector_type(8)));
typedef _Float16 half4v __attribute__((ext_vector_type(4)));
typedef float    f32x16 __attribute__((ext_vector_type(16)));

#define GLOAD_LDS16(gp, lp) __builtin_amdgcn_global_load_lds( \
    (const __attribute__((address_space(1))) void*)(gp),      \
    (__attribute__((address_space(3))) void*)(lp), 16, 0, 0)

// Packed fragment layout for an [R][K] f16 plane (K pow2):
// (r,k) -> (r>>5)*(32K) + (k>>4)*512 + ((k>>3)&1)*256 + (r&31)*8 + (k&7)
__device__ __forceinline__ size_t packoff(int r, int k, int K) {
    return (size_t)(r >> 5) * (size_t)(32 * K) + (size_t)(k >> 4) * 512
         + (size_t)((k >> 3) & 1) * 256 + (size_t)(r & 31) * 8 + (size_t)(k & 7);
}

// ---------------------------------------------------------------------------
// Static device buffers — write-before-read each call.
// value = hi + lo/4096 (lo pre-scaled by 2^12)
// ---------------------------------------------------------------------------
__device__ _Float16 g_curh[BQ*EDIM], g_curl[BQ*EDIM];       // packed K=512
__device__ _Float16 g_h0h[BQ*HDIM], g_h0l[BQ*HDIM];         // packed K=1024
__device__ _Float16 g_h1h[BQ*HDIM], g_h1l[BQ*HDIM];         // packed K=1024
__device__ _Float16 g_hnh[BQ*HDIM], g_hnl[BQ*HDIM];         // packed K=1024
__device__ float    g_c0[BQ*HDIM], g_c1[BQ*HDIM];

__device__ _Float16 g_wih0h[4*HDIM*EDIM], g_wih0l[4*HDIM*EDIM];  // packed K=512
__device__ _Float16 g_whh0h[4*HDIM*HDIM], g_whh0l[4*HDIM*HDIM];  // packed K=1024
__device__ _Float16 g_wih1h[4*HDIM*HDIM], g_wih1l[4*HDIM*HDIM];  // packed K=1024
__device__ _Float16 g_whh1h[4*HDIM*HDIM], g_whh1l[4*HDIM*HDIM];  // packed K=1024
__device__ _Float16 g_wouth[VDIM*HDIM],   g_woutl[VDIM*HDIM];    // packed K=1024

__device__ float g_part_g[4 * PGS];    // gate split-K partials (S=4)
__device__ float g_part_lg[8 * PLS];   // logits split-K partials (S=8)
__device__ float g_bsum0[4*HDIM], g_bsum1[4*HDIM];

// ---------------------------------------------------------------------------
__global__ void init_kernel(float* __restrict__ out,
                            const float* __restrict__ bi0, const float* __restrict__ bh0,
                            const float* __restrict__ bi1, const float* __restrict__ bh1) {
    int i = blockIdx.x * 256 + threadIdx.x;   // [0, BQ*HDIM)
    g_c0[i] = 0.f; g_c1[i] = 0.f;
    g_h0h[i] = (_Float16)0.f; g_h0l[i] = (_Float16)0.f;
    g_h1h[i] = (_Float16)0.f; g_h1l[i] = (_Float16)0.f;
    if (i < 4 * HDIM) {
        g_bsum0[i] = bi0[i] + bh0[i];
        g_bsum1[i] = bi1[i] + bh1[i];
    }
    if (i < 3 * BQ) {
        int which = i / BQ, b = i % BQ;
        out[(size_t)which * BQ * TOUT + (size_t)b * TOUT + (TOUT - 1)] = 0.f;
    }
}

// ---------------------------------------------------------------------------
// fp32 [R][K] -> packed (hi, lo*2^12) f16 planes. klog = log2(K).
// ---------------------------------------------------------------------------
__global__ void split_pack_kernel(const float* __restrict__ w, _Float16* __restrict__ hi,
                                  _Float16* __restrict__ lo, int klog, int nquads) {
    int q = blockIdx.x * 256 + threadIdx.x;
    if (q >= nquads) return;
    int e = q * 4;
    int r = e >> klog, k = e & ((1 << klog) - 1);
    float4 v = ((const float4*)w)[q];
    half4v h, l;
    h[0] = (_Float16)v.x; l[0] = (_Float16)((v.x - (float)h[0]) * 4096.f);
    h[1] = (_Float16)v.y; l[1] = (_Float16)((v.y - (float)h[1]) * 4096.f);
    h[2] = (_Float16)v.z; l[2] = (_Float16)((v.z - (float)h[2]) * 4096.f);
    h[3] = (_Float16)v.w; l[3] = (_Float16)((v.w - (float)h[3]) * 4096.f);
    size_t po = packoff(r, k, 1 << klog);
    *(half4v*)&hi[po] = h;
    *(half4v*)&lo[po] = l;
}

__device__ __forceinline__ void split1(float x, _Float16* hp, _Float16* lp) {
    _Float16 h = (_Float16)x;
    *hp = h;
    *lp = (_Float16)((x - (float)h) * 4096.f);
}

// ---------------------------------------------------------------------------
// Register-blocked MFMA GEMM, A-in-LDS / B-in-VGPR. 128x128 tile, 4 waves
// (2mw x 2nw), each wave a 64x64 quadrant, acc[2][2]x{M,L}. BK=16.
// A: 8 frags/iter (2pl x 4mf) -> LDS via global_load_lds (2/wave), 4-slot x
// 8KB rotation, depth-2. B: per-wave private strips -> 2 named VGPR sets,
// depth-1 (4 x half8 global loads/iter). Issue order B-then-A keeps A's
// 2-deep lead; steady vmcnt(8) (= A(it+1)2 + B(it+1)4 + A(it+2)2), tail 6/0.
// setprio(1) around MFMA cluster. LDS traffic halved vs all-LDS (24KB/iter).
// ---------------------------------------------------------------------------
__global__ __launch_bounds__(256, 2) void gemm_rb(
    const _Float16* __restrict__ Ah1, const _Float16* __restrict__ Al1, int K1,
    const _Float16* __restrict__ Wh1, const _Float16* __restrict__ Wl1,
    const _Float16* __restrict__ Ah2, const _Float16* __restrict__ Al2, int K2,
    const _Float16* __restrict__ Wh2, const _Float16* __restrict__ Wl2,
    float* __restrict__ outp, int N, int S, int NTP)
{
    __shared__ __align__(16) _Float16 sA[4][2][4][512]; // [slot][pl][mf] 32KB
    int tid = threadIdx.x;
    int l = tid & 63, w = tid >> 6;          // w in [0,4)
    int lr = l & 31, lq = l >> 5;
    int mw = w >> 1, nw = w & 1;

    int wb = blockIdx.x;
    int xcd = wb & 7, q = wb >> 3;
    int nt = xcd * NTP + q % NTP;            // n-tile (128 wide)
    int rest = q / NTP;
    int s = rest % S;
    int mb = rest / S;                        // m-tile (128 rows)

    int kch1 = K1 / S, kch2 = (K2 > 0) ? (K2 / S) : 0;
    int n1 = kch1 >> 4;                       // BK=16 iters in source 1
    int nit = n1 + (kch2 >> 4);               // even (24 / 32 / 8)

    // ---- A staging: wave w stages frags f = 2w, 2w+1 (f = pl*4 + mf) ----
    const _Float16* fsrcA1[2];
    const _Float16* fsrcA2[2];
    _Float16* fdstA[2];
    #pragma unroll
    for (int qq = 0; qq < 2; ++qq) {
        int f = w * 2 + qq;
        int pl = f >> 2, mf = f & 3;
        const _Float16* p1 = pl ? Al1 : Ah1;
        fsrcA1[qq] = p1 + (size_t)(mb * 4 + mf) * (size_t)(32 * K1)
                   + (size_t)((s * kch1) >> 4) * 512 + (size_t)l * 8;
        if (K2 > 0) {
            const _Float16* p2 = pl ? Al2 : Ah2;
            fsrcA2[qq] = p2 + (size_t)(mb * 4 + mf) * (size_t)(32 * K2)
                       + (size_t)((s * kch2) >> 4) * 512 + (size_t)l * 8;
        } else {
            fsrcA2[qq] = fsrcA1[qq];
        }
        fdstA[qq] = &sA[0][pl][mf][0];
    }

    // ---- B pointers: wave's private strips nt*4 + 2nw+{0,1}, planes h/l ----
    const _Float16 *pB1[4], *pB2[4];   // [pl*2+j]
    #pragma unroll
    for (int pj = 0; pj < 4; ++pj) {
        int pl = pj >> 1, j = pj & 1;
        const _Float16* p1 = pl ? Wl1 : Wh1;
        pB1[pj] = p1 + (size_t)(nt * 4 + 2 * nw + j) * (size_t)(32 * K1)
                + (size_t)((s * kch1) >> 4) * 512 + (size_t)l * 8;
        if (K2 > 0) {
            const _Float16* p2 = pl ? Wl2 : Wh2;
            pB2[pj] = p2 + (size_t)(nt * 4 + 2 * nw + j) * (size_t)(32 * K2)
                    + (size_t)((s * kch2) >> 4) * 512 + (size_t)l * 8;
        } else {
            pB2[pj] = pB1[pj];
        }
    }

    f32x16 accM00 = {}, accM01 = {}, accM10 = {}, accM11 = {};
    f32x16 accL00 = {}, accL01 = {}, accL10 = {}, accL11 = {};

    half8 B0h0, B0h1, B0l0, B0l1;   // set 0
    half8 B1h0, B1h1, B1l0, B1l1;   // set 1

#define STAGE_A(IT, SLOT)                                                      \
    {                                                                          \
        int it_ = (IT);                                                        \
        bool g1_ = it_ < n1;                                                   \
        size_t off_ = (size_t)(g1_ ? it_ : it_ - n1) * 512;                    \
        _Pragma("unroll")                                                      \
        for (int qq = 0; qq < 2; ++qq) {                                       \
            const _Float16* sp_ = (g1_ ? fsrcA1[qq] : fsrcA2[qq]) + off_;      \
            GLOAD_LDS16(sp_, fdstA[qq] + (size_t)(SLOT) * 4096);               \
        }                                                                      \
    }

#define LOAD_B(IT, BH0, BH1, BL0, BL1)                                         \
    {                                                                          \
        int it_ = (IT);                                                        \
        bool g1_ = it_ < n1;                                                   \
        size_t off_ = (size_t)(g1_ ? it_ : it_ - n1) * 512;                    \
        BH0 = *(const half8*)((g1_ ? pB1[0] : pB2[0]) + off_);                 \
        BH1 = *(const half8*)((g1_ ? pB1[1] : pB2[1]) + off_);                 \
        BL0 = *(const half8*)((g1_ ? pB1[2] : pB2[2]) + off_);                 \
        BL1 = *(const half8*)((g1_ ? pB1[3] : pB2[3]) + off_);                 \
    }

#define COMPUTE(SLOT, BH0, BH1, BL0, BL1)                                      \
    {                                                                          \
        half8 ah0 = *(const half8*)&sA[SLOT][0][2*mw  ][(size_t)l * 8];        \
        half8 ah1 = *(const half8*)&sA[SLOT][0][2*mw+1][(size_t)l * 8];        \
        half8 al0 = *(const half8*)&sA[SLOT][1][2*mw  ][(size_t)l * 8];        \
        half8 al1 = *(const half8*)&sA[SLOT][1][2*mw+1][(size_t)l * 8];        \
        __builtin_amdgcn_s_setprio(1);                                         \
        accM00 = __builtin_amdgcn_mfma_f32_32x32x16_f16(ah0, BH0, accM00, 0, 0, 0); \
        accM01 = __builtin_amdgcn_mfma_f32_32x32x16_f16(ah0, BH1, accM01, 0, 0, 0); \
        accM10 = __builtin_amdgcn_mfma_f32_32x32x16_f16(ah1, BH0, accM10, 0, 0, 0); \
        accM11 = __builtin_amdgcn_mfma_f32_32x32x16_f16(ah1, BH1, accM11, 0, 0, 0); \
        accL00 = __builtin_amdgcn_mfma_f32_32x32x16_f16(ah0, BL0, accL00, 0, 0, 0); \
        accL01 = __builtin_amdgcn_mfma_f32_32x32x16_f16(ah0, BL1, accL01, 0, 0, 0); \
        accL10 = __builtin_amdgcn_mfma_f32_32x32x16_f16(ah1, BL0, accL10, 0, 0, 0); \
        accL11 = __builtin_amdgcn_mfma_f32_32x32x16_f16(ah1, BL1, accL11, 0, 0, 0); \
        accL00 = __builtin_amdgcn_mfma_f32_32x32x16_f16(al0, BH0, accL00, 0, 0, 0); \
        accL01 = __builtin_amdgcn_mfma_f32_32x32x16_f16(al0, BH1, accL01, 0, 0, 0); \
        accL10 = __builtin_amdgcn_mfma_f32_32x32x16_f16(al1, BH0, accL10, 0, 0, 0); \
        accL11 = __builtin_amdgcn_mfma_f32_32x32x16_f16(al1, BH1, accL11, 0, 0, 0); \
        __builtin_amdgcn_s_setprio(0);                                         \
    }

#define WAITSYNC(IT)                                                           \
    {                                                                          \
        int rem_ = nit - 1 - (IT);                                             \
        if (rem_ >= 2)      asm volatile("s_waitcnt vmcnt(8)" ::: "memory");   \
        else if (rem_ == 1) asm volatile("s_waitcnt vmcnt(6)" ::: "memory");   \
        else                asm volatile("s_waitcnt vmcnt(0)" ::: "memory");   \
        __builtin_amdgcn_sched_barrier(0);                                     \
        __builtin_amdgcn_s_barrier();                                          \
    }

    // prologue: A(0), B(0), A(1)  — waiting for B(0) later keeps A(1) in flight
    STAGE_A(0, 0);
    LOAD_B(0, B0h0, B0h1, B0l0, B0l1);
    STAGE_A(1, 1);

    for (int it = 0; it < nit; it += 2) {      // nit even
        if (it + 1 < nit) LOAD_B(it + 1, B1h0, B1h1, B1l0, B1l1);
        if (it + 2 < nit) STAGE_A(it + 2, (it + 2) & 3);
        WAITSYNC(it);
        COMPUTE(it & 3, B0h0, B0h1, B0l0, B0l1);

        if (it + 2 < nit) LOAD_B(it + 2, B0h0, B0h1, B0l0, B0l1);
        if (it + 3 < nit) STAGE_A(it + 3, (it + 3) & 3);
        WAITSYNC(it + 1);
        COMPUTE((it + 1) & 3, B1h0, B1h1, B1l0, B1l1);
    }
#undef WAITSYNC
#undef COMPUTE
#undef LOAD_B
#undef STAGE_A

    // epilogue: C/D layout n = l&31, m = (r&3)+8*(r>>2)+4*(l>>5)
    float* op = outp + (size_t)s * BQ * N;
    #pragma unroll
    for (int mi = 0; mi < 2; ++mi) {
        int m0 = mb * 128 + (mw * 2 + mi) * 32;
        #pragma unroll
        for (int ni = 0; ni < 2; ++ni) {
            int n = nt * 128 + (nw * 2 + ni) * 32 + lr;
            const f32x16* aM = (mi == 0) ? (ni == 0 ? &accM00 : &accM01)
                                         : (ni == 0 ? &accM10 : &accM11);
            const f32x16* aL = (mi == 0) ? (ni == 0 ? &accL00 : &accL01)
                                         : (ni == 0 ? &accL10 : &accL11);
            #pragma unroll
            for (int r = 0; r < 16; ++r) {
                int row = (r & 3) + 8 * (r >> 2) + 4 * lq;
                op[(size_t)(m0 + row) * N + n] = (*aM)[r] + (*aL)[r] * (1.f / 4096.f);
            }
        }
    }
}

// ---------------------------------------------------------------------------
// fp32 GEMM for inp = x @ w_in^T + b_in (once, K=64); writes packed cur
// ---------------------------------------------------------------------------
#define GBK 16
#define GPAD 68
__global__ __launch_bounds__(256) void gemm_in(const float* __restrict__ x,
                                               const float* __restrict__ w_in,
                                               const float* __restrict__ b_in) {
    __shared__ __align__(16) float As[GBK][GPAD];
    __shared__ __align__(16) float Bs[GBK][GPAD];
    int tid = threadIdx.x;
    int tx = tid & 15, ty = tid >> 4;
    int m0 = blockIdx.y * 64, n0 = blockIdx.x * 64;
    int lm = tid >> 2, lk = (tid & 3) << 2;
    const int K = 64;
    float acc[4][4] = {};
    for (int k0 = 0; k0 < K; k0 += GBK) {
        float4 av = *(const float4*)(x + (size_t)(m0 + lm) * K + k0 + lk);
        float4 wv = *(const float4*)(w_in + (size_t)(n0 + lm) * K + k0 + lk);
        As[lk + 0][lm] = av.x; As[lk + 1][lm] = av.y;
        As[lk + 2][lm] = av.z; As[lk + 3][lm] = av.w;
        Bs[lk + 0][lm] = wv.x; Bs[lk + 1][lm] = wv.y;
        Bs[lk + 2][lm] = wv.z; Bs[lk + 3][lm] = wv.w;
        __syncthreads();
        #pragma unroll
        for (int kk = 0; kk < GBK; ++kk) {
            float4 a  = *(const float4*)&As[kk][ty * 4];
            float4 bq = *(const float4*)&Bs[kk][tx * 4];
            float aa[4] = {a.x, a.y, a.z, a.w};
            float bb[4] = {bq.x, bq.y, bq.z, bq.w};
            #pragma unroll
            for (int i = 0; i < 4; ++i)
                #pragma unroll
                for (int j = 0; j < 4; ++j)
                    acc[i][j] = fmaf(aa[i], bb[j], acc[i][j]);
        }
        __syncthreads();
    }
    #pragma unroll
    for (int i = 0; i < 4; ++i) {
        int m = m0 + ty * 4 + i;
        int n = n0 + tx * 4;
        half4v h, lo;
        #pragma unroll
        for (int j = 0; j < 4; ++j) {
            float v = acc[i][j] + b_in[n + j];
            _Float16 hv = (_Float16)v;
            h[j] = hv;
            lo[j] = (_Float16)((v - (float)hv) * 4096.f);
        }
        size_t po = packoff(m, n, EDIM);
        *(half4v*)&g_curh[po] = h;
        *(half4v*)&g_curl[po] = lo;
    }
}

__device__ __forceinline__ float sigm(float x) { return 1.f / (1.f + expf(-x)); }

// ---------------------------------------------------------------------------
// LSTM cell 0: gates = sum of 4 partials + bsum0 -> h0 (packed), c0.
// ---------------------------------------------------------------------------
__global__ void lstm0_kernel() {
    int qidx = blockIdx.x * 256 + threadIdx.x;
    int b = qidx >> 8;
    int j = (qidx & 255) * 4;
    size_t base = (size_t)b * 4096;
    float4 G[4];
    #pragma unroll
    for (int g = 0; g < 4; ++g) {
        float4 bs = *(const float4*)&g_bsum0[g * 1024 + j];
        G[g] = bs;
        #pragma unroll
        for (int s = 0; s < 4; ++s) {
            float4 p = *(const float4*)&g_part_g[(size_t)s * PGS + base + g * 1024 + j];
            G[g].x += p.x; G[g].y += p.y; G[g].z += p.z; G[g].w += p.w;
        }
    }
    size_t hb = (size_t)b * HDIM + j;
    float4 cin = *(const float4*)&g_c0[hb];
    float ci[4] = {cin.x, cin.y, cin.z, cin.w};
    float gi[4] = {G[0].x, G[0].y, G[0].z, G[0].w};
    float gf[4] = {G[1].x, G[1].y, G[1].z, G[1].w};
    float gg[4] = {G[2].x, G[2].y, G[2].z, G[2].w};
    float go[4] = {G[3].x, G[3].y, G[3].z, G[3].w};
    float c[4], h[4];
    half4v hh, hl;
    #pragma unroll
    for (int r = 0; r < 4; ++r) {
        c[r] = sigm(gf[r]) * ci[r] + sigm(gi[r]) * tanhf(gg[r]);
        h[r] = sigm(go[r]) * tanhf(c[r]);
        _Float16 hi16 = (_Float16)h[r];
        hh[r] = hi16;
        hl[r] = (_Float16)((h[r] - (float)hi16) * 4096.f);
    }
    *(float4*)&g_c0[hb] = {c[0], c[1], c[2], c[3]};
    size_t po = packoff(b, j, HDIM);
    *(half4v*)&g_h0h[po] = hh;
    *(half4v*)&g_h0l[po] = hl;
}

// ---------------------------------------------------------------------------
// LSTM cell 1 + LayerNorm: one block per row; writes packed h1, hn.
// ---------------------------------------------------------------------------
__global__ __launch_bounds__(256) void lstm1_ln_kernel(
    const float* __restrict__ ln_g, const float* __restrict__ ln_b)
{
    __shared__ float sbuf[4];
    int b = blockIdx.x, tid = threadIdx.x;
    int lane = tid & 63, wid = tid >> 6;
    int j = tid * 4;
    size_t base = (size_t)b * 4096;
    float4 G[4];
    #pragma unroll
    for (int g = 0; g < 4; ++g) {
        float4 bs = *(const float4*)&g_bsum1[g * 1024 + j];
        G[g] = bs;
        #pragma unroll
        for (int s = 0; s < 4; ++s) {
            float4 p = *(const float4*)&g_part_g[(size_t)s * PGS + base + g * 1024 + j];
            G[g].x += p.x; G[g].y += p.y; G[g].z += p.z; G[g].w += p.w;
        }
    }
    size_t hb = (size_t)b * HDIM + j;
    float4 cin = *(const float4*)&g_c1[hb];
    float ci[4] = {cin.x, cin.y, cin.z, cin.w};
    float gi[4] = {G[0].x, G[0].y, G[0].z, G[0].w};
    float gf[4] = {G[1].x, G[1].y, G[1].z, G[1].w};
    float gg[4] = {G[2].x, G[2].y, G[2].z, G[2].w};
    float go[4] = {G[3].x, G[3].y, G[3].z, G[3].w};
    float c[4], h[4];
    float sum = 0.f;
    #pragma unroll
    for (int r = 0; r < 4; ++r) {
        c[r] = sigm(gf[r]) * ci[r] + sigm(gi[r]) * tanhf(gg[r]);
        h[r] = sigm(go[r]) * tanhf(c[r]);
        sum += h[r];
    }
    *(float4*)&g_c1[hb] = {c[0], c[1], c[2], c[3]};
    size_t po = packoff(b, j, HDIM);
    half4v h1h, h1l;
    #pragma unroll
    for (int r = 0; r < 4; ++r) {
        _Float16 hi16 = (_Float16)h[r];
        h1h[r] = hi16;
        h1l[r] = (_Float16)((h[r] - (float)hi16) * 4096.f);
    }
    *(half4v*)&g_h1h[po] = h1h;
    *(half4v*)&g_h1l[po] = h1l;

    for (int off = 32; off > 0; off >>= 1) sum += __shfl_down(sum, off, 64);
    if (lane == 0) sbuf[wid] = sum;
    __syncthreads();
    float mu = (sbuf[0] + sbuf[1] + sbuf[2] + sbuf[3]) * (1.f / HDIM);
    __syncthreads();
    float sq = 0.f;
    #pragma unroll
    for (int r = 0; r < 4; ++r) { float d = h[r] - mu; sq += d * d; }
    for (int off = 32; off > 0; off >>= 1) sq += __shfl_down(sq, off, 64);
    if (lane == 0) sbuf[wid] = sq;
    __syncthreads();
    float var = (sbuf[0] + sbuf[1] + sbuf[2] + sbuf[3]) * (1.f / HDIM);
    float rstd = 1.f / sqrtf(var + 1e-5f);
    half4v nh, nl;
    #pragma unroll
    for (int r = 0; r < 4; ++r) {
        float hn = (h[r] - mu) * rstd * ln_g[j + r] + ln_b[j + r];
        _Float16 hi16 = (_Float16)hn;
        nh[r] = hi16;
        nl[r] = (_Float16)((hn - (float)hi16) * 4096.f);
    }
    *(half4v*)&g_hnh[po] = nh;
    *(half4v*)&g_hnl[po] = nl;
}

// ---------------------------------------------------------------------------
// per-row softmax over logits = sum of 8 partials + b_out; writes packed cur
// ---------------------------------------------------------------------------
__global__ __launch_bounds__(256) void softmax_row_kernel(
    const float* __restrict__ b_out, const float* __restrict__ emb,
    float* __restrict__ out, int t)
{
    __shared__ float swv[4];
    __shared__ int   swi[4];
    __shared__ float sZ[4], sS[4];
    __shared__ float s_max;
    __shared__ int   s_idx;
    int b = blockIdx.x, tid = threadIdx.x;
    int lane = tid & 63, wid = tid >> 6;
    size_t base = (size_t)b * VDIM + 4 * tid;
    float4 xv = *(const float4*)&b_out[4 * tid];
    #pragma unroll
    for (int s = 0; s < 8; ++s) {
        float4 p = *(const float4*)&g_part_lg[(size_t)s * PLS + base];
        xv.x += p.x; xv.y += p.y; xv.z += p.z; xv.w += p.w;
    }

    float mv = xv.x; int mi = 4 * tid;
    if (xv.y > mv) { mv = xv.y; mi = 4 * tid + 1; }
    if (xv.z > mv) { mv = xv.z; mi = 4 * tid + 2; }
    if (xv.w > mv) { mv = xv.w; mi = 4 * tid + 3; }
    for (int off = 32; off > 0; off >>= 1) {
        float ov = __shfl_down(mv, off, 64);
        int   oi = __shfl_down(mi, off, 64);
        if (ov > mv || (ov == mv && oi < mi)) { mv = ov; mi = oi; }
    }
    if (lane == 0) { swv[wid] = mv; swi[wid] = mi; }
    __syncthreads();
    if (tid == 0) {
        mv = swv[0]; mi = swi[0];
        for (int w = 1; w < 4; ++w)
            if (swv[w] > mv || (swv[w] == mv && swi[w] < mi)) { mv = swv[w]; mi = swi[w]; }
        s_max = mv; s_idx = mi;
    }
    __syncthreads();
    float xmax = s_max;

    float sv[4] = {xv.x - xmax, xv.y - xmax, xv.z - xmax, xv.w - xmax};
    float z = 0.f, s1 = 0.f;
    #pragma unroll
    for (int r = 0; r < 4; ++r) { float e = expf(sv[r]); z += e; s1 += e * sv[r]; }
    for (int off = 32; off > 0; off >>= 1) {
        z  += __shfl_down(z, off, 64);
        s1 += __shfl_down(s1, off, 64);
    }
    if (lane == 0) { sZ[wid] = z; sS[wid] = s1; }
    __syncthreads();
    if (tid == 0) {
        float Z = sZ[0] + sZ[1] + sZ[2] + sZ[3];
        float S1 = sS[0] + sS[1] + sS[2] + sS[3];
        float logZ = logf(Z);
        float ent = logZ - S1 / Z;
        out[(size_t)b * TOUT + t]                         = (float)s_idx;
        out[(size_t)BQ * TOUT + (size_t)b * TOUT + t]     = -logZ;
        out[(size_t)2 * BQ * TOUT + (size_t)b * TOUT + t] = ent;
    }
    __syncthreads();
    int sym = s_idx;
    const float* e = emb + (size_t)sym * EDIM;
    for (int j = tid; j < EDIM; j += 256) {
        size_t po = packoff(b, j, EDIM);
        split1(e[j], &g_curh[po], &g_curl[po]);
    }
}

// ---------------------------------------------------------------------------
extern "C" void kernel_launch(void* const* d_in, const int* in_sizes, int n_in,
                              void* d_out, int out_size, void* d_ws, size_t ws_size,
                              hipStream_t stream) {
    const float* x     = (const float*)d_in[0];
    const float* w_in  = (const float*)d_in[1];
    const float* b_in  = (const float*)d_in[2];
    const float* w_ih0 = (const float*)d_in[3];
    const float* w_hh0 = (const float*)d_in[4];
    const float* b_ih0 = (const float*)d_in[5];
    const float* b_hh0 = (const float*)d_in[6];
    const float* w_ih1 = (const float*)d_in[7];
    const float* w_hh1 = (const float*)d_in[8];
    const float* b_ih1 = (const float*)d_in[9];
    const float* b_hh1 = (const float*)d_in[10];
    const float* ln_g  = (const float*)d_in[11];
    const float* ln_b  = (const float*)d_in[12];
    const float* w_out = (const float*)d_in[13];
    const float* b_out = (const float*)d_in[14];
    const float* emb   = (const float*)d_in[15];
    float* out = (float*)d_out;

    _Float16 *wih0h, *wih0l, *whh0h, *whh0l, *wih1h, *wih1l, *whh1h, *whh1l, *wouth, *woutl;
    hipGetSymbolAddress((void**)&wih0h, HIP_SYMBOL(g_wih0h));
    hipGetSymbolAddress((void**)&wih0l, HIP_SYMBOL(g_wih0l));
    hipGetSymbolAddress((void**)&whh0h, HIP_SYMBOL(g_whh0h));
    hipGetSymbolAddress((void**)&whh0l, HIP_SYMBOL(g_whh0l));
    hipGetSymbolAddress((void**)&wih1h, HIP_SYMBOL(g_wih1h));
    hipGetSymbolAddress((void**)&wih1l, HIP_SYMBOL(g_wih1l));
    hipGetSymbolAddress((void**)&whh1h, HIP_SYMBOL(g_whh1h));
    hipGetSymbolAddress((void**)&whh1l, HIP_SYMBOL(g_whh1l));
    hipGetSymbolAddress((void**)&wouth, HIP_SYMBOL(g_wouth));
    hipGetSymbolAddress((void**)&woutl, HIP_SYMBOL(g_woutl));
    _Float16 *curh, *curl, *h0h, *h0l, *h1h, *h1l, *hnh, *hnl;
    hipGetSymbolAddress((void**)&curh, HIP_SYMBOL(g_curh));
    hipGetSymbolAddress((void**)&curl, HIP_SYMBOL(g_curl));
    hipGetSymbolAddress((void**)&h0h, HIP_SYMBOL(g_h0h));
    hipGetSymbolAddress((void**)&h0l, HIP_SYMBOL(g_h0l));
    hipGetSymbolAddress((void**)&h1h, HIP_SYMBOL(g_h1h));
    hipGetSymbolAddress((void**)&h1l, HIP_SYMBOL(g_h1l));
    hipGetSymbolAddress((void**)&hnh, HIP_SYMBOL(g_hnh));
    hipGetSymbolAddress((void**)&hnl, HIP_SYMBOL(g_hnl));
    float *part_g, *part_lg;
    hipGetSymbolAddress((void**)&part_g, HIP_SYMBOL(g_part_g));
    hipGetSymbolAddress((void**)&part_lg, HIP_SYMBOL(g_part_lg));

    init_kernel<<<(BQ * HDIM) / 256, 256, 0, stream>>>(out, b_ih0, b_hh0, b_ih1, b_hh1);

    // one-time weight split+pack (klog = log2 K)
    split_pack_kernel<<<(4*HDIM*EDIM/4 + 255)/256, 256, 0, stream>>>(w_ih0, wih0h, wih0l, 9,  4*HDIM*EDIM/4);
    split_pack_kernel<<<(4*HDIM*HDIM/4 + 255)/256, 256, 0, stream>>>(w_hh0, whh0h, whh0l, 10, 4*HDIM*HDIM/4);
    split_pack_kernel<<<(4*HDIM*HDIM/4 + 255)/256, 256, 0, stream>>>(w_ih1, wih1h, wih1l, 10, 4*HDIM*HDIM/4);
    split_pack_kernel<<<(4*HDIM*HDIM/4 + 255)/256, 256, 0, stream>>>(w_hh1, whh1h, whh1l, 10, 4*HDIM*HDIM/4);
    split_pack_kernel<<<(VDIM*HDIM/4 + 255)/256, 256, 0, stream>>>(w_out, wouth, woutl, 10, VDIM*HDIM/4);

    gemm_in<<<dim3(EDIM / 64, BQ / 64), 256, 0, stream>>>(x, w_in, b_in);

    for (int t = 0; t < TLEN; ++t) {
        // gates0 = cur @ w_ih0^T + h0 @ w_hh0^T   (S=4 -> 4 part_g planes; grid 512)
        gemm_rb<<<512, 256, 0, stream>>>(
            curh, curl, EDIM, wih0h, wih0l,
            h0h, h0l, HDIM, whh0h, whh0l,
            part_g, 4 * HDIM, 4, 4);
        lstm0_kernel<<<(BQ * HDIM / 4) / 256, 256, 0, stream>>>();

        // gates1 = h0 @ w_ih1^T + h1 @ w_hh1^T   (S=4 -> 4 part_g planes; grid 512)
        gemm_rb<<<512, 256, 0, stream>>>(
            h0h, h0l, HDIM, wih1h, wih1l,
            h1h, h1l, HDIM, whh1h, whh1l,
            part_g, 4 * HDIM, 4, 4);
        lstm1_ln_kernel<<<BQ, 256, 0, stream>>>(ln_g, ln_b);

        // logits partials = hn @ w_out^T   (S=8 -> 8 planes; grid 256)
        gemm_rb<<<256, 256, 0, stream>>>(
            hnh, hnl, HDIM, wouth, woutl,
            (const _Float16*)nullptr, (const _Float16*)nullptr, 0,
            (const _Float16*)nullptr, (const _Float16*)nullptr,
            part_lg, VDIM, 8, 1);

        softmax_row_kernel<<<BQ, 256, 0, stream>>>(b_out, emb, out, t);
    }
}

// Round 14
// 2994.282 us; speedup vs baseline: 1.0444x; 1.0444x over previous
//
#include <hip/hip_runtime.h>
#include <hip/hip_bf16.h>
#include <math.h>

#define BQ   512
#define EDIM 512
#define HDIM 1024
#define VDIM 1024
#define TLEN 32
#define TOUT 33
#define PGS  (BQ * 4 * HDIM)   // gate partial plane stride
#define PLS  (BQ * VDIM)       // logits partial plane stride

typedef _Float16 half8  __attribute__((ext_vector_type(8)));
typedef _Float16 half4v __attribute__((ext_vector_type(4)));
typedef float    f32x16 __attribute__((ext_vector_type(16)));

#define GLOAD_LDS16(gp, lp) __builtin_amdgcn_global_load_lds( \
    (const __attribute__((address_space(1))) void*)(gp),      \
    (__attribute__((address_space(3))) void*)(lp), 16, 0, 0)

// Packed fragment layout for an [R][K] f16 plane (K pow2):
// (r,k) -> (r>>5)*(32K) + (k>>4)*512 + ((k>>3)&1)*256 + (r&31)*8 + (k&7)
__device__ __forceinline__ size_t packoff(int r, int k, int K) {
    return (size_t)(r >> 5) * (size_t)(32 * K) + (size_t)(k >> 4) * 512
         + (size_t)((k >> 3) & 1) * 256 + (size_t)(r & 31) * 8 + (size_t)(k & 7);
}

// ---------------------------------------------------------------------------
// Static device buffers — write-before-read each call.
// value = hi + lo/4096 (lo pre-scaled by 2^12)
// ---------------------------------------------------------------------------
__device__ _Float16 g_curh[BQ*EDIM], g_curl[BQ*EDIM];       // packed K=512
__device__ _Float16 g_h0h[BQ*HDIM], g_h0l[BQ*HDIM];         // packed K=1024
__device__ _Float16 g_h1h[BQ*HDIM], g_h1l[BQ*HDIM];         // packed K=1024
__device__ _Float16 g_hnh[BQ*HDIM], g_hnl[BQ*HDIM];         // packed K=1024
__device__ float    g_c0[BQ*HDIM], g_c1[BQ*HDIM];

__device__ _Float16 g_wih0h[4*HDIM*EDIM], g_wih0l[4*HDIM*EDIM];  // packed K=512
__device__ _Float16 g_whh0h[4*HDIM*HDIM], g_whh0l[4*HDIM*HDIM];  // packed K=1024
__device__ _Float16 g_wih1h[4*HDIM*HDIM], g_wih1l[4*HDIM*HDIM];  // packed K=1024
__device__ _Float16 g_whh1h[4*HDIM*HDIM], g_whh1l[4*HDIM*HDIM];  // packed K=1024
__device__ _Float16 g_wouth[VDIM*HDIM],   g_woutl[VDIM*HDIM];    // packed K=1024

__device__ float g_part_g[4 * PGS];    // gate split-K partials (S=4)
__device__ float g_part_lg[8 * PLS];   // logits split-K partials (S=8)
__device__ float g_bsum0[4*HDIM], g_bsum1[4*HDIM];

// ---------------------------------------------------------------------------
__global__ void init_kernel(float* __restrict__ out,
                            const float* __restrict__ bi0, const float* __restrict__ bh0,
                            const float* __restrict__ bi1, const float* __restrict__ bh1) {
    int i = blockIdx.x * 256 + threadIdx.x;   // [0, BQ*HDIM)
    g_c0[i] = 0.f; g_c1[i] = 0.f;
    g_h0h[i] = (_Float16)0.f; g_h0l[i] = (_Float16)0.f;
    g_h1h[i] = (_Float16)0.f; g_h1l[i] = (_Float16)0.f;
    if (i < 4 * HDIM) {
        g_bsum0[i] = bi0[i] + bh0[i];
        g_bsum1[i] = bi1[i] + bh1[i];
    }
    if (i < 3 * BQ) {
        int which = i / BQ, b = i % BQ;
        out[(size_t)which * BQ * TOUT + (size_t)b * TOUT + (TOUT - 1)] = 0.f;
    }
}

// ---------------------------------------------------------------------------
// fp32 [R][K] -> packed (hi, lo*2^12) f16 planes. klog = log2(K).
// ---------------------------------------------------------------------------
__global__ void split_pack_kernel(const float* __restrict__ w, _Float16* __restrict__ hi,
                                  _Float16* __restrict__ lo, int klog, int nquads) {
    int q = blockIdx.x * 256 + threadIdx.x;
    if (q >= nquads) return;
    int e = q * 4;
    int r = e >> klog, k = e & ((1 << klog) - 1);
    float4 v = ((const float4*)w)[q];
    half4v h, l;
    h[0] = (_Float16)v.x; l[0] = (_Float16)((v.x - (float)h[0]) * 4096.f);
    h[1] = (_Float16)v.y; l[1] = (_Float16)((v.y - (float)h[1]) * 4096.f);
    h[2] = (_Float16)v.z; l[2] = (_Float16)((v.z - (float)h[2]) * 4096.f);
    h[3] = (_Float16)v.w; l[3] = (_Float16)((v.w - (float)h[3]) * 4096.f);
    size_t po = packoff(r, k, 1 << klog);
    *(half4v*)&hi[po] = h;
    *(half4v*)&lo[po] = l;
}

__device__ __forceinline__ void split1(float x, _Float16* hp, _Float16* lp) {
    _Float16 h = (_Float16)x;
    *hp = h;
    *lp = (_Float16)((x - (float)h) * 4096.f);
}

// ---------------------------------------------------------------------------
// Phase-split MFMA GEMM (m201-shaped). 128x128 tile, 4 waves (2mw x 2nw),
// each wave a 64x64 quadrant, acc[2][2]x{M,L}. BK=32 per barrier:
// ONE s_barrier + ONE counted vmcnt(8) per 24-MFMA cluster. 2-slot LDS
// (A 16KB + B 16KB per slot = 64KB total -> 2 blocks/CU), depth-1 staging
// (8 gload_lds per wave per iter). Two kh-phases per iter (8 ds_read +
// 12 MFMA each) interleaved by the compiler's lgkmcnt scheduling; setprio
// around MFMA clusters. Slot safety: stage (it+1)&1 while reading it&1.
// ---------------------------------------------------------------------------
__global__ __launch_bounds__(256, 2) void gemm_rb(
    const _Float16* __restrict__ Ah1, const _Float16* __restrict__ Al1, int K1,
    const _Float16* __restrict__ Wh1, const _Float16* __restrict__ Wl1,
    const _Float16* __restrict__ Ah2, const _Float16* __restrict__ Al2, int K2,
    const _Float16* __restrict__ Wh2, const _Float16* __restrict__ Wl2,
    float* __restrict__ outp, int N, int S, int NTP)
{
    __shared__ __align__(16) _Float16 sA[2][2][4][2][512]; // [slot][pl][mf][kh] 32KB
    __shared__ __align__(16) _Float16 sB[2][2][4][2][512]; // [slot][pl][nf][kh] 32KB
    int tid = threadIdx.x;
    int l = tid & 63, w = tid >> 6;          // w in [0,4)
    int lr = l & 31, lq = l >> 5;
    int mw = w >> 1, nw = w & 1;

    int wb = blockIdx.x;
    int xcd = wb & 7, q = wb >> 3;
    int nt = xcd * NTP + q % NTP;            // n-tile (128 wide)
    int rest = q / NTP;
    int s = rest % S;
    int mb = rest / S;                        // m-tile (128 rows)

    int kch1 = K1 / S, kch2 = (K2 > 0) ? (K2 / S) : 0;
    int n1 = kch1 >> 5;                       // BK=32 iters in source 1
    int nit = n1 + (kch2 >> 5);               // gates1: 16, gates0: 12, logits: 4

    // per-wave staging: 8 frags (1KB each) of the 32-frag BK=32 slot.
    // f = w*8+qq; f<16 -> A(a=f: pl=a>>3, mf=(a>>1)&3, kh=a&1); else B.
    const _Float16* fsrc1[8];
    const _Float16* fsrc2[8];
    _Float16* fdst0[8];
    #pragma unroll
    for (int qq = 0; qq < 8; ++qq) {
        int f = w * 8 + qq;
        bool isA = f < 16;
        int r_ = isA ? f : f - 16;
        int pl = r_ >> 3, idx = (r_ >> 1) & 3, kh = r_ & 1;
        int strip = isA ? (mb * 4 + idx) : (nt * 4 + idx);
        const _Float16* p1 = isA ? (pl ? Al1 : Ah1) : (pl ? Wl1 : Wh1);
        fsrc1[qq] = p1 + (size_t)strip * (size_t)(32 * K1)
                  + (size_t)((s * kch1) >> 4) * 512 + (size_t)kh * 512 + (size_t)l * 8;
        if (K2 > 0) {
            const _Float16* p2 = isA ? (pl ? Al2 : Ah2) : (pl ? Wl2 : Wh2);
            fsrc2[qq] = p2 + (size_t)strip * (size_t)(32 * K2)
                      + (size_t)((s * kch2) >> 4) * 512 + (size_t)kh * 512 + (size_t)l * 8;
        } else {
            fsrc2[qq] = fsrc1[qq];
        }
        fdst0[qq] = isA ? &sA[0][pl][idx][kh][0] : &sB[0][pl][idx][kh][0];
    }

    f32x16 accM00 = {}, accM01 = {}, accM10 = {}, accM11 = {};
    f32x16 accL00 = {}, accL01 = {}, accL10 = {}, accL11 = {};

#define STAGE(IT, SLOT)                                                        \
    {                                                                          \
        int it_ = (IT);                                                        \
        bool g1_ = it_ < n1;                                                   \
        size_t off_ = (size_t)(g1_ ? it_ : it_ - n1) * 1024;                   \
        _Pragma("unroll")                                                      \
        for (int qq = 0; qq < 8; ++qq) {                                       \
            const _Float16* sp_ = (g1_ ? fsrc1[qq] : fsrc2[qq]) + off_;        \
            GLOAD_LDS16(sp_, fdst0[qq] + (size_t)(SLOT) * 8192);               \
        }                                                                      \
    }

#define COMPUTE(SLOT, KH)                                                      \
    {                                                                          \
        half8 ah0 = *(const half8*)&sA[SLOT][0][2*mw  ][KH][(size_t)l * 8];    \
        half8 ah1 = *(const half8*)&sA[SLOT][0][2*mw+1][KH][(size_t)l * 8];    \
        half8 al0 = *(const half8*)&sA[SLOT][1][2*mw  ][KH][(size_t)l * 8];    \
        half8 al1 = *(const half8*)&sA[SLOT][1][2*mw+1][KH][(size_t)l * 8];    \
        half8 bh0 = *(const half8*)&sB[SLOT][0][2*nw  ][KH][(size_t)l * 8];    \
        half8 bh1 = *(const half8*)&sB[SLOT][0][2*nw+1][KH][(size_t)l * 8];    \
        half8 bl0 = *(const half8*)&sB[SLOT][1][2*nw  ][KH][(size_t)l * 8];    \
        half8 bl1 = *(const half8*)&sB[SLOT][1][2*nw+1][KH][(size_t)l * 8];    \
        __builtin_amdgcn_s_setprio(1);                                         \
        accM00 = __builtin_amdgcn_mfma_f32_32x32x16_f16(ah0, bh0, accM00, 0, 0, 0); \
        accM01 = __builtin_amdgcn_mfma_f32_32x32x16_f16(ah0, bh1, accM01, 0, 0, 0); \
        accM10 = __builtin_amdgcn_mfma_f32_32x32x16_f16(ah1, bh0, accM10, 0, 0, 0); \
        accM11 = __builtin_amdgcn_mfma_f32_32x32x16_f16(ah1, bh1, accM11, 0, 0, 0); \
        accL00 = __builtin_amdgcn_mfma_f32_32x32x16_f16(ah0, bl0, accL00, 0, 0, 0); \
        accL01 = __builtin_amdgcn_mfma_f32_32x32x16_f16(ah0, bl1, accL01, 0, 0, 0); \
        accL10 = __builtin_amdgcn_mfma_f32_32x32x16_f16(ah1, bl0, accL10, 0, 0, 0); \
        accL11 = __builtin_amdgcn_mfma_f32_32x32x16_f16(ah1, bl1, accL11, 0, 0, 0); \
        accL00 = __builtin_amdgcn_mfma_f32_32x32x16_f16(al0, bh0, accL00, 0, 0, 0); \
        accL01 = __builtin_amdgcn_mfma_f32_32x32x16_f16(al0, bh1, accL01, 0, 0, 0); \
        accL10 = __builtin_amdgcn_mfma_f32_32x32x16_f16(al1, bh0, accL10, 0, 0, 0); \
        accL11 = __builtin_amdgcn_mfma_f32_32x32x16_f16(al1, bh1, accL11, 0, 0, 0); \
        __builtin_amdgcn_s_setprio(0);                                         \
    }

    STAGE(0, 0);
    for (int it = 0; it < nit; ++it) {
        if (it + 1 < nit) {
            STAGE(it + 1, (it + 1) & 1);
            asm volatile("s_waitcnt vmcnt(8)" ::: "memory");   // drain stage(it)
        } else {
            asm volatile("s_waitcnt vmcnt(0)" ::: "memory");
        }
        __builtin_amdgcn_sched_barrier(0);
        __builtin_amdgcn_s_barrier();
        COMPUTE(it & 1, 0);
        COMPUTE(it & 1, 1);
    }
#undef COMPUTE
#undef STAGE

    // epilogue: C/D layout n = l&31, m = (r&3)+8*(r>>2)+4*(l>>5)
    float* op = outp + (size_t)s * BQ * N;
    #pragma unroll
    for (int mi = 0; mi < 2; ++mi) {
        int m0 = mb * 128 + (mw * 2 + mi) * 32;
        #pragma unroll
        for (int ni = 0; ni < 2; ++ni) {
            int n = nt * 128 + (nw * 2 + ni) * 32 + lr;
            const f32x16* aM = (mi == 0) ? (ni == 0 ? &accM00 : &accM01)
                                         : (ni == 0 ? &accM10 : &accM11);
            const f32x16* aL = (mi == 0) ? (ni == 0 ? &accL00 : &accL01)
                                         : (ni == 0 ? &accL10 : &accL11);
            #pragma unroll
            for (int r = 0; r < 16; ++r) {
                int row = (r & 3) + 8 * (r >> 2) + 4 * lq;
                op[(size_t)(m0 + row) * N + n] = (*aM)[r] + (*aL)[r] * (1.f / 4096.f);
            }
        }
    }
}

// ---------------------------------------------------------------------------
// fp32 GEMM for inp = x @ w_in^T + b_in (once, K=64); writes packed cur
// ---------------------------------------------------------------------------
#define GBK 16
#define GPAD 68
__global__ __launch_bounds__(256) void gemm_in(const float* __restrict__ x,
                                               const float* __restrict__ w_in,
                                               const float* __restrict__ b_in) {
    __shared__ __align__(16) float As[GBK][GPAD];
    __shared__ __align__(16) float Bs[GBK][GPAD];
    int tid = threadIdx.x;
    int tx = tid & 15, ty = tid >> 4;
    int m0 = blockIdx.y * 64, n0 = blockIdx.x * 64;
    int lm = tid >> 2, lk = (tid & 3) << 2;
    const int K = 64;
    float acc[4][4] = {};
    for (int k0 = 0; k0 < K; k0 += GBK) {
        float4 av = *(const float4*)(x + (size_t)(m0 + lm) * K + k0 + lk);
        float4 wv = *(const float4*)(w_in + (size_t)(n0 + lm) * K + k0 + lk);
        As[lk + 0][lm] = av.x; As[lk + 1][lm] = av.y;
        As[lk + 2][lm] = av.z; As[lk + 3][lm] = av.w;
        Bs[lk + 0][lm] = wv.x; Bs[lk + 1][lm] = wv.y;
        Bs[lk + 2][lm] = wv.z; Bs[lk + 3][lm] = wv.w;
        __syncthreads();
        #pragma unroll
        for (int kk = 0; kk < GBK; ++kk) {
            float4 a  = *(const float4*)&As[kk][ty * 4];
            float4 bq = *(const float4*)&Bs[kk][tx * 4];
            float aa[4] = {a.x, a.y, a.z, a.w};
            float bb[4] = {bq.x, bq.y, bq.z, bq.w};
            #pragma unroll
            for (int i = 0; i < 4; ++i)
                #pragma unroll
                for (int j = 0; j < 4; ++j)
                    acc[i][j] = fmaf(aa[i], bb[j], acc[i][j]);
        }
        __syncthreads();
    }
    #pragma unroll
    for (int i = 0; i < 4; ++i) {
        int m = m0 + ty * 4 + i;
        int n = n0 + tx * 4;
        half4v h, lo;
        #pragma unroll
        for (int j = 0; j < 4; ++j) {
            float v = acc[i][j] + b_in[n + j];
            _Float16 hv = (_Float16)v;
            h[j] = hv;
            lo[j] = (_Float16)((v - (float)hv) * 4096.f);
        }
        size_t po = packoff(m, n, EDIM);
        *(half4v*)&g_curh[po] = h;
        *(half4v*)&g_curl[po] = lo;
    }
}

__device__ __forceinline__ float sigm(float x) { return 1.f / (1.f + expf(-x)); }

// ---------------------------------------------------------------------------
// LSTM cell 0: gates = sum of 4 partials + bsum0 -> h0 (packed), c0.
// ---------------------------------------------------------------------------
__global__ void lstm0_kernel() {
    int qidx = blockIdx.x * 256 + threadIdx.x;
    int b = qidx >> 8;
    int j = (qidx & 255) * 4;
    size_t base = (size_t)b * 4096;
    float4 G[4];
    #pragma unroll
    for (int g = 0; g < 4; ++g) {
        float4 bs = *(const float4*)&g_bsum0[g * 1024 + j];
        G[g] = bs;
        #pragma unroll
        for (int s = 0; s < 4; ++s) {
            float4 p = *(const float4*)&g_part_g[(size_t)s * PGS + base + g * 1024 + j];
            G[g].x += p.x; G[g].y += p.y; G[g].z += p.z; G[g].w += p.w;
        }
    }
    size_t hb = (size_t)b * HDIM + j;
    float4 cin = *(const float4*)&g_c0[hb];
    float ci[4] = {cin.x, cin.y, cin.z, cin.w};
    float gi[4] = {G[0].x, G[0].y, G[0].z, G[0].w};
    float gf[4] = {G[1].x, G[1].y, G[1].z, G[1].w};
    float gg[4] = {G[2].x, G[2].y, G[2].z, G[2].w};
    float go[4] = {G[3].x, G[3].y, G[3].z, G[3].w};
    float c[4], h[4];
    half4v hh, hl;
    #pragma unroll
    for (int r = 0; r < 4; ++r) {
        c[r] = sigm(gf[r]) * ci[r] + sigm(gi[r]) * tanhf(gg[r]);
        h[r] = sigm(go[r]) * tanhf(c[r]);
        _Float16 hi16 = (_Float16)h[r];
        hh[r] = hi16;
        hl[r] = (_Float16)((h[r] - (float)hi16) * 4096.f);
    }
    *(float4*)&g_c0[hb] = {c[0], c[1], c[2], c[3]};
    size_t po = packoff(b, j, HDIM);
    *(half4v*)&g_h0h[po] = hh;
    *(half4v*)&g_h0l[po] = hl;
}

// ---------------------------------------------------------------------------
// LSTM cell 1 + LayerNorm: one block per row; writes packed h1, hn.
// ---------------------------------------------------------------------------
__global__ __launch_bounds__(256) void lstm1_ln_kernel(
    const float* __restrict__ ln_g, const float* __restrict__ ln_b)
{
    __shared__ float sbuf[4];
    int b = blockIdx.x, tid = threadIdx.x;
    int lane = tid & 63, wid = tid >> 6;
    int j = tid * 4;
    size_t base = (size_t)b * 4096;
    float4 G[4];
    #pragma unroll
    for (int g = 0; g < 4; ++g) {
        float4 bs = *(const float4*)&g_bsum1[g * 1024 + j];
        G[g] = bs;
        #pragma unroll
        for (int s = 0; s < 4; ++s) {
            float4 p = *(const float4*)&g_part_g[(size_t)s * PGS + base + g * 1024 + j];
            G[g].x += p.x; G[g].y += p.y; G[g].z += p.z; G[g].w += p.w;
        }
    }
    size_t hb = (size_t)b * HDIM + j;
    float4 cin = *(const float4*)&g_c1[hb];
    float ci[4] = {cin.x, cin.y, cin.z, cin.w};
    float gi[4] = {G[0].x, G[0].y, G[0].z, G[0].w};
    float gf[4] = {G[1].x, G[1].y, G[1].z, G[1].w};
    float gg[4] = {G[2].x, G[2].y, G[2].z, G[2].w};
    float go[4] = {G[3].x, G[3].y, G[3].z, G[3].w};
    float c[4], h[4];
    float sum = 0.f;
    #pragma unroll
    for (int r = 0; r < 4; ++r) {
        c[r] = sigm(gf[r]) * ci[r] + sigm(gi[r]) * tanhf(gg[r]);
        h[r] = sigm(go[r]) * tanhf(c[r]);
        sum += h[r];
    }
    *(float4*)&g_c1[hb] = {c[0], c[1], c[2], c[3]};
    size_t po = packoff(b, j, HDIM);
    half4v h1h, h1l;
    #pragma unroll
    for (int r = 0; r < 4; ++r) {
        _Float16 hi16 = (_Float16)h[r];
        h1h[r] = hi16;
        h1l[r] = (_Float16)((h[r] - (float)hi16) * 4096.f);
    }
    *(half4v*)&g_h1h[po] = h1h;
    *(half4v*)&g_h1l[po] = h1l;

    for (int off = 32; off > 0; off >>= 1) sum += __shfl_down(sum, off, 64);
    if (lane == 0) sbuf[wid] = sum;
    __syncthreads();
    float mu = (sbuf[0] + sbuf[1] + sbuf[2] + sbuf[3]) * (1.f / HDIM);
    __syncthreads();
    float sq = 0.f;
    #pragma unroll
    for (int r = 0; r < 4; ++r) { float d = h[r] - mu; sq += d * d; }
    for (int off = 32; off > 0; off >>= 1) sq += __shfl_down(sq, off, 64);
    if (lane == 0) sbuf[wid] = sq;
    __syncthreads();
    float var = (sbuf[0] + sbuf[1] + sbuf[2] + sbuf[3]) * (1.f / HDIM);
    float rstd = 1.f / sqrtf(var + 1e-5f);
    half4v nh, nl;
    #pragma unroll
    for (int r = 0; r < 4; ++r) {
        float hn = (h[r] - mu) * rstd * ln_g[j + r] + ln_b[j + r];
        _Float16 hi16 = (_Float16)hn;
        nh[r] = hi16;
        nl[r] = (_Float16)((hn - (float)hi16) * 4096.f);
    }
    *(half4v*)&g_hnh[po] = nh;
    *(half4v*)&g_hnl[po] = nl;
}

// ---------------------------------------------------------------------------
// per-row softmax over logits = sum of 8 partials + b_out; writes packed cur
// ---------------------------------------------------------------------------
__global__ __launch_bounds__(256) void softmax_row_kernel(
    const float* __restrict__ b_out, const float* __restrict__ emb,
    float* __restrict__ out, int t)
{
    __shared__ float swv[4];
    __shared__ int   swi[4];
    __shared__ float sZ[4], sS[4];
    __shared__ float s_max;
    __shared__ int   s_idx;
    int b = blockIdx.x, tid = threadIdx.x;
    int lane = tid & 63, wid = tid >> 6;
    size_t base = (size_t)b * VDIM + 4 * tid;
    float4 xv = *(const float4*)&b_out[4 * tid];
    #pragma unroll
    for (int s = 0; s < 8; ++s) {
        float4 p = *(const float4*)&g_part_lg[(size_t)s * PLS + base];
        xv.x += p.x; xv.y += p.y; xv.z += p.z; xv.w += p.w;
    }

    float mv = xv.x; int mi = 4 * tid;
    if (xv.y > mv) { mv = xv.y; mi = 4 * tid + 1; }
    if (xv.z > mv) { mv = xv.z; mi = 4 * tid + 2; }
    if (xv.w > mv) { mv = xv.w; mi = 4 * tid + 3; }
    for (int off = 32; off > 0; off >>= 1) {
        float ov = __shfl_down(mv, off, 64);
        int   oi = __shfl_down(mi, off, 64);
        if (ov > mv || (ov == mv && oi < mi)) { mv = ov; mi = oi; }
    }
    if (lane == 0) { swv[wid] = mv; swi[wid] = mi; }
    __syncthreads();
    if (tid == 0) {
        mv = swv[0]; mi = swi[0];
        for (int w = 1; w < 4; ++w)
            if (swv[w] > mv || (swv[w] == mv && swi[w] < mi)) { mv = swv[w]; mi = swi[w]; }
        s_max = mv; s_idx = mi;
    }
    __syncthreads();
    float xmax = s_max;

    float sv[4] = {xv.x - xmax, xv.y - xmax, xv.z - xmax, xv.w - xmax};
    float z = 0.f, s1 = 0.f;
    #pragma unroll
    for (int r = 0; r < 4; ++r) { float e = expf(sv[r]); z += e; s1 += e * sv[r]; }
    for (int off = 32; off > 0; off >>= 1) {
        z  += __shfl_down(z, off, 64);
        s1 += __shfl_down(s1, off, 64);
    }
    if (lane == 0) { sZ[wid] = z; sS[wid] = s1; }
    __syncthreads();
    if (tid == 0) {
        float Z = sZ[0] + sZ[1] + sZ[2] + sZ[3];
        float S1 = sS[0] + sS[1] + sS[2] + sS[3];
        float logZ = logf(Z);
        float ent = logZ - S1 / Z;
        out[(size_t)b * TOUT + t]                         = (float)s_idx;
        out[(size_t)BQ * TOUT + (size_t)b * TOUT + t]     = -logZ;
        out[(size_t)2 * BQ * TOUT + (size_t)b * TOUT + t] = ent;
    }
    __syncthreads();
    int sym = s_idx;
    const float* e = emb + (size_t)sym * EDIM;
    for (int j = tid; j < EDIM; j += 256) {
        size_t po = packoff(b, j, EDIM);
        split1(e[j], &g_curh[po], &g_curl[po]);
    }
}

// ---------------------------------------------------------------------------
extern "C" void kernel_launch(void* const* d_in, const int* in_sizes, int n_in,
                              void* d_out, int out_size, void* d_ws, size_t ws_size,
                              hipStream_t stream) {
    const float* x     = (const float*)d_in[0];
    const float* w_in  = (const float*)d_in[1];
    const float* b_in  = (const float*)d_in[2];
    const float* w_ih0 = (const float*)d_in[3];
    const float* w_hh0 = (const float*)d_in[4];
    const float* b_ih0 = (const float*)d_in[5];
    const float* b_hh0 = (const float*)d_in[6];
    const float* w_ih1 = (const float*)d_in[7];
    const float* w_hh1 = (const float*)d_in[8];
    const float* b_ih1 = (const float*)d_in[9];
    const float* b_hh1 = (const float*)d_in[10];
    const float* ln_g  = (const float*)d_in[11];
    const float* ln_b  = (const float*)d_in[12];
    const float* w_out = (const float*)d_in[13];
    const float* b_out = (const float*)d_in[14];
    const float* emb   = (const float*)d_in[15];
    float* out = (float*)d_out;

    _Float16 *wih0h, *wih0l, *whh0h, *whh0l, *wih1h, *wih1l, *whh1h, *whh1l, *wouth, *woutl;
    hipGetSymbolAddress((void**)&wih0h, HIP_SYMBOL(g_wih0h));
    hipGetSymbolAddress((void**)&wih0l, HIP_SYMBOL(g_wih0l));
    hipGetSymbolAddress((void**)&whh0h, HIP_SYMBOL(g_whh0h));
    hipGetSymbolAddress((void**)&whh0l, HIP_SYMBOL(g_whh0l));
    hipGetSymbolAddress((void**)&wih1h, HIP_SYMBOL(g_wih1h));
    hipGetSymbolAddress((void**)&wih1l, HIP_SYMBOL(g_wih1l));
    hipGetSymbolAddress((void**)&whh1h, HIP_SYMBOL(g_whh1h));
    hipGetSymbolAddress((void**)&whh1l, HIP_SYMBOL(g_whh1l));
    hipGetSymbolAddress((void**)&wouth, HIP_SYMBOL(g_wouth));
    hipGetSymbolAddress((void**)&woutl, HIP_SYMBOL(g_woutl));
    _Float16 *curh, *curl, *h0h, *h0l, *h1h, *h1l, *hnh, *hnl;
    hipGetSymbolAddress((void**)&curh, HIP_SYMBOL(g_curh));
    hipGetSymbolAddress((void**)&curl, HIP_SYMBOL(g_curl));
    hipGetSymbolAddress((void**)&h0h, HIP_SYMBOL(g_h0h));
    hipGetSymbolAddress((void**)&h0l, HIP_SYMBOL(g_h0l));
    hipGetSymbolAddress((void**)&h1h, HIP_SYMBOL(g_h1h));
    hipGetSymbolAddress((void**)&h1l, HIP_SYMBOL(g_h1l));
    hipGetSymbolAddress((void**)&hnh, HIP_SYMBOL(g_hnh));
    hipGetSymbolAddress((void**)&hnl, HIP_SYMBOL(g_hnl));
    float *part_g, *part_lg;
    hipGetSymbolAddress((void**)&part_g, HIP_SYMBOL(g_part_g));
    hipGetSymbolAddress((void**)&part_lg, HIP_SYMBOL(g_part_lg));

    init_kernel<<<(BQ * HDIM) / 256, 256, 0, stream>>>(out, b_ih0, b_hh0, b_ih1, b_hh1);

    // one-time weight split+pack (klog = log2 K)
    split_pack_kernel<<<(4*HDIM*EDIM/4 + 255)/256, 256, 0, stream>>>(w_ih0, wih0h, wih0l, 9,  4*HDIM*EDIM/4);
    split_pack_kernel<<<(4*HDIM*HDIM/4 + 255)/256, 256, 0, stream>>>(w_hh0, whh0h, whh0l, 10, 4*HDIM*HDIM/4);
    split_pack_kernel<<<(4*HDIM*HDIM/4 + 255)/256, 256, 0, stream>>>(w_ih1, wih1h, wih1l, 10, 4*HDIM*HDIM/4);
    split_pack_kernel<<<(4*HDIM*HDIM/4 + 255)/256, 256, 0, stream>>>(w_hh1, whh1h, whh1l, 10, 4*HDIM*HDIM/4);
    split_pack_kernel<<<(VDIM*HDIM/4 + 255)/256, 256, 0, stream>>>(w_out, wouth, woutl, 10, VDIM*HDIM/4);

    gemm_in<<<dim3(EDIM / 64, BQ / 64), 256, 0, stream>>>(x, w_in, b_in);

    for (int t = 0; t < TLEN; ++t) {
        // gates0 = cur @ w_ih0^T + h0 @ w_hh0^T   (S=4 -> 4 part_g planes; grid 512)
        gemm_rb<<<512, 256, 0, stream>>>(
            curh, curl, EDIM, wih0h, wih0l,
            h0h, h0l, HDIM, whh0h, whh0l,
            part_g, 4 * HDIM, 4, 4);
        lstm0_kernel<<<(BQ * HDIM / 4) / 256, 256, 0, stream>>>();

        // gates1 = h0 @ w_ih1^T + h1 @ w_hh1^T   (S=4 -> 4 part_g planes; grid 512)
        gemm_rb<<<512, 256, 0, stream>>>(
            h0h, h0l, HDIM, wih1h, wih1l,
            h1h, h1l, HDIM, whh1h, whh1l,
            part_g, 4 * HDIM, 4, 4);
        lstm1_ln_kernel<<<BQ, 256, 0, stream>>>(ln_g, ln_b);

        // logits partials = hn @ w_out^T   (S=8 -> 8 planes; grid 256)
        gemm_rb<<<256, 256, 0, stream>>>(
            hnh, hnl, HDIM, wouth, woutl,
            (const _Float16*)nullptr, (const _Float16*)nullptr, 0,
            (const _Float16*)nullptr, (const _Float16*)nullptr,
            part_lg, VDIM, 8, 1);

        softmax_row_kernel<<<BQ, 256, 0, stream>>>(b_out, emb, out, t);
    }
}

// Round 15
// 2846.998 us; speedup vs baseline: 1.0984x; 1.0517x over previous
//
#include <hip/hip_runtime.h>
#include <hip/hip_bf16.h>
#include <math.h>

#define BQ   512
#define EDIM 512
#define HDIM 1024
#define VDIM 1024
#define TLEN 32
#define TOUT 33
#define PGS  (BQ * 4 * HDIM)   // gate partial plane stride
#define PLS  (BQ * VDIM)       // logits partial plane stride

typedef _Float16 half8  __attribute__((ext_vector_type(8)));
typedef _Float16 half4v __attribute__((ext_vector_type(4)));
typedef float    f32x16 __attribute__((ext_vector_type(16)));

#define GLOAD_LDS16(gp, lp) __builtin_amdgcn_global_load_lds( \
    (const __attribute__((address_space(1))) void*)(gp),      \
    (__attribute__((address_space(3))) void*)(lp), 16, 0, 0)

// Packed fragment layout for an [R][K] f16 plane (K pow2):
// (r,k) -> (r>>5)*(32K) + (k>>4)*512 + ((k>>3)&1)*256 + (r&31)*8 + (k&7)
// each (32-row strip, 16-k block) = contiguous 1KB; lane l owns row (l&31),
// k-half (l>>5) -> exactly an MFMA 32x32x16 fragment.
__device__ __forceinline__ size_t packoff(int r, int k, int K) {
    return (size_t)(r >> 5) * (size_t)(32 * K) + (size_t)(k >> 4) * 512
         + (size_t)((k >> 3) & 1) * 256 + (size_t)(r & 31) * 8 + (size_t)(k & 7);
}

// ---------------------------------------------------------------------------
// Static device buffers — write-before-read each call.
// value = hi + lo/4096 (lo pre-scaled by 2^12)
// ---------------------------------------------------------------------------
__device__ _Float16 g_curh[BQ*EDIM], g_curl[BQ*EDIM];       // packed K=512
__device__ _Float16 g_h0h[BQ*HDIM], g_h0l[BQ*HDIM];         // packed K=1024
__device__ _Float16 g_h1h[BQ*HDIM], g_h1l[BQ*HDIM];         // packed K=1024
__device__ _Float16 g_hnh[BQ*HDIM], g_hnl[BQ*HDIM];         // packed K=1024
__device__ float    g_c0[BQ*HDIM], g_c1[BQ*HDIM];

__device__ _Float16 g_wih0h[4*HDIM*EDIM], g_wih0l[4*HDIM*EDIM];  // packed K=512
__device__ _Float16 g_whh0h[4*HDIM*HDIM], g_whh0l[4*HDIM*HDIM];  // packed K=1024
__device__ _Float16 g_wih1h[4*HDIM*HDIM], g_wih1l[4*HDIM*HDIM];  // packed K=1024
__device__ _Float16 g_whh1h[4*HDIM*HDIM], g_whh1l[4*HDIM*HDIM];  // packed K=1024
__device__ _Float16 g_wouth[VDIM*HDIM],   g_woutl[VDIM*HDIM];    // packed K=1024

__device__ float g_part_g[2 * PGS];    // gate split-K partials (S=2)
__device__ float g_part_lg[8 * PLS];   // logits split-K partials (S=8)
__device__ float g_bsum0[4*HDIM], g_bsum1[4*HDIM];

// ---------------------------------------------------------------------------
__global__ void init_kernel(float* __restrict__ out,
                            const float* __restrict__ bi0, const float* __restrict__ bh0,
                            const float* __restrict__ bi1, const float* __restrict__ bh1) {
    int i = blockIdx.x * 256 + threadIdx.x;   // [0, BQ*HDIM)
    g_c0[i] = 0.f; g_c1[i] = 0.f;
    g_h0h[i] = (_Float16)0.f; g_h0l[i] = (_Float16)0.f;
    g_h1h[i] = (_Float16)0.f; g_h1l[i] = (_Float16)0.f;
    if (i < 4 * HDIM) {
        g_bsum0[i] = bi0[i] + bh0[i];
        g_bsum1[i] = bi1[i] + bh1[i];
    }
    if (i < 3 * BQ) {
        int which = i / BQ, b = i % BQ;
        out[(size_t)which * BQ * TOUT + (size_t)b * TOUT + (TOUT - 1)] = 0.f;
    }
}

// ---------------------------------------------------------------------------
// fp32 [R][K] -> packed (hi, lo*2^12) f16 planes. klog = log2(K).
// ---------------------------------------------------------------------------
__global__ void split_pack_kernel(const float* __restrict__ w, _Float16* __restrict__ hi,
                                  _Float16* __restrict__ lo, int klog, int nquads) {
    int q = blockIdx.x * 256 + threadIdx.x;
    if (q >= nquads) return;
    int e = q * 4;
    int r = e >> klog, k = e & ((1 << klog) - 1);
    float4 v = ((const float4*)w)[q];
    half4v h, l;
    h[0] = (_Float16)v.x; l[0] = (_Float16)((v.x - (float)h[0]) * 4096.f);
    h[1] = (_Float16)v.y; l[1] = (_Float16)((v.y - (float)h[1]) * 4096.f);
    h[2] = (_Float16)v.z; l[2] = (_Float16)((v.z - (float)h[2]) * 4096.f);
    h[3] = (_Float16)v.w; l[3] = (_Float16)((v.w - (float)h[3]) * 4096.f);
    size_t po = packoff(r, k, 1 << klog);
    *(half4v*)&hi[po] = h;
    *(half4v*)&lo[po] = l;
}

__device__ __forceinline__ void split1(float x, _Float16* hp, _Float16* lp) {
    _Float16 h = (_Float16)x;
    *hp = h;
    *lp = (_Float16)((x - (float)h) * 4096.f);
}

// ---------------------------------------------------------------------------
// 128x128 MFMA GEMM, 512 threads / 8 waves (r9 best-measured config).
// Wave w = (mw = w>>2, nw = w&3) owns 64m x 32n (m-frags 2mw, 2mw+1).
// A AND B staged to LDS (fragment-linear, conflict-free) via global_load_lds
// from packed planes: 32 frags/iter, 4 per wave. 4-slot LDS rotation staged
// 2 iters ahead; counted vmcnt(8/4/0) + raw s_barrier. setprio around the
// MFMA cluster (T5). Split-K over s. nit % 4 == 0. XCD-slab n-tiles.
// ---------------------------------------------------------------------------
__global__ __launch_bounds__(512, 2) void gemm_big(
    const _Float16* __restrict__ Ah1, const _Float16* __restrict__ Al1, int K1,
    const _Float16* __restrict__ Wh1, const _Float16* __restrict__ Wl1,
    const _Float16* __restrict__ Ah2, const _Float16* __restrict__ Al2, int K2,
    const _Float16* __restrict__ Wh2, const _Float16* __restrict__ Wl2,
    const float* __restrict__ bias, float* __restrict__ outp,
    int N, int S, int NTP)
{
    __shared__ __align__(16) _Float16 sA[4][2][4][2][512]; // [slot][pl][mf][kh] 64KB
    __shared__ __align__(16) _Float16 sB[4][2][4][2][512]; // [slot][pl][nw][kh] 64KB
    int tid = threadIdx.x;
    int l = tid & 63, w = tid >> 6;          // w in [0,8)
    int lr = l & 31, lq = l >> 5;
    int mw = w >> 2, nw = w & 3;

    int wb = blockIdx.x;
    int xcd = wb & 7, q = wb >> 3;
    int nt = xcd * NTP + q % NTP;            // n-tile (128 wide)
    int rest = q / NTP;
    int s = rest % S;
    int mb = rest / S;                        // m-tile (128 rows)

    int kch1 = K1 / S, kch2 = (K2 > 0) ? (K2 / S) : 0;
    int n1 = kch1 >> 5;
    int nit = n1 + (kch2 >> 5);

    // ---- per-wave staging assignment: frags q = w*4 + qq, qq in [0,4) ----
    const _Float16* fsrc1[4];
    const _Float16* fsrc2[4];
    _Float16* fdst0[4];
    #pragma unroll
    for (int qq = 0; qq < 4; ++qq) {
        int fq = w * 4 + qq;                 // [0,32)
        bool isA = fq < 16;
        int r_ = isA ? fq : fq - 16;
        int pl = r_ >> 3, idx = (r_ >> 1) & 3, kh = r_ & 1;
        int strip = isA ? (mb * 4 + idx) : (nt * 4 + idx);
        const _Float16* p1 = isA ? (pl ? Al1 : Ah1) : (pl ? Wl1 : Wh1);
        fsrc1[qq] = p1 + (size_t)strip * (size_t)(32 * K1)
                  + (size_t)((s * kch1) >> 4) * 512 + (size_t)kh * 512 + (size_t)l * 8;
        if (K2 > 0) {
            const _Float16* p2 = isA ? (pl ? Al2 : Ah2) : (pl ? Wl2 : Wh2);
            fsrc2[qq] = p2 + (size_t)strip * (size_t)(32 * K2)
                      + (size_t)((s * kch2) >> 4) * 512 + (size_t)kh * 512 + (size_t)l * 8;
        } else {
            fsrc2[qq] = fsrc1[qq];
        }
        fdst0[qq] = isA ? &sA[0][pl][idx][kh][0] : &sB[0][pl][idx][kh][0];
    }

    f32x16 accM0 = {}, accM1 = {}, accL0 = {}, accL1 = {};

#define STAGE(IT, SLOT)                                                        \
    {                                                                          \
        int it_ = (IT);                                                        \
        bool g1_ = it_ < n1;                                                   \
        size_t off_ = (size_t)(g1_ ? it_ : it_ - n1) * 1024;                   \
        _Pragma("unroll")                                                      \
        for (int qq = 0; qq < 4; ++qq) {                                       \
            const _Float16* sp_ = (g1_ ? fsrc1[qq] : fsrc2[qq]) + off_;        \
            GLOAD_LDS16(sp_, fdst0[qq] + (size_t)(SLOT) * 8192);               \
        }                                                                      \
    }

#define COMPUTE(BUF)                                                           \
    {                                                                          \
        __builtin_amdgcn_s_setprio(1);                                         \
        _Pragma("unroll")                                                      \
        for (int kh_ = 0; kh_ < 2; ++kh_) {                                    \
            half8 ah0 = *(const half8*)&sA[BUF][0][2*mw  ][kh_][(size_t)l * 8];\
            half8 ah1 = *(const half8*)&sA[BUF][0][2*mw+1][kh_][(size_t)l * 8];\
            half8 al0 = *(const half8*)&sA[BUF][1][2*mw  ][kh_][(size_t)l * 8];\
            half8 al1 = *(const half8*)&sA[BUF][1][2*mw+1][kh_][(size_t)l * 8];\
            half8 bh  = *(const half8*)&sB[BUF][0][nw][kh_][(size_t)l * 8];    \
            half8 bl  = *(const half8*)&sB[BUF][1][nw][kh_][(size_t)l * 8];    \
            accM0 = __builtin_amdgcn_mfma_f32_32x32x16_f16(ah0, bh, accM0, 0, 0, 0); \
            accM1 = __builtin_amdgcn_mfma_f32_32x32x16_f16(ah1, bh, accM1, 0, 0, 0); \
            accL0 = __builtin_amdgcn_mfma_f32_32x32x16_f16(ah0, bl, accL0, 0, 0, 0); \
            accL1 = __builtin_amdgcn_mfma_f32_32x32x16_f16(ah1, bl, accL1, 0, 0, 0); \
            accL0 = __builtin_amdgcn_mfma_f32_32x32x16_f16(al0, bh, accL0, 0, 0, 0); \
            accL1 = __builtin_amdgcn_mfma_f32_32x32x16_f16(al1, bh, accL1, 0, 0, 0); \
        }                                                                      \
        __builtin_amdgcn_s_setprio(0);                                         \
    }

// per-wave 4 VMEM/iter; 2 groups in flight => vmcnt(8) steady state
#define WAITSYNC(IT)                                                           \
    {                                                                          \
        if ((IT) < nit - 2)       asm volatile("s_waitcnt vmcnt(8)" ::: "memory"); \
        else if ((IT) == nit - 2) asm volatile("s_waitcnt vmcnt(4)" ::: "memory"); \
        else                      asm volatile("s_waitcnt vmcnt(0)" ::: "memory"); \
        __builtin_amdgcn_sched_barrier(0);                                     \
        __builtin_amdgcn_s_barrier();                                          \
    }

#define ITER(IT, BUF)                                                          \
    {                                                                          \
        if ((IT) + 2 < nit) STAGE((IT) + 2, ((BUF) + 2) & 3);                  \
        WAITSYNC(IT);                                                          \
        COMPUTE(BUF);                                                          \
    }

    STAGE(0, 0);
    STAGE(1, 1);
    for (int base = 0; base < nit; base += 4) {   // nit in {4, 24, 32}
        ITER(base + 0, 0);
        ITER(base + 1, 1);
        ITER(base + 2, 2);
        ITER(base + 3, 3);
    }
#undef ITER
#undef WAITSYNC
#undef COMPUTE
#undef STAGE

    // epilogue: C/D layout n = l&31, m = (r&3)+8*(r>>2)+4*(l>>5)
    int n = nt * 128 + nw * 32 + lr;
    int m0 = mb * 128 + mw * 64;
    float bv = bias ? bias[n] : 0.f;
    float* op = outp + (size_t)s * BQ * N;
    #pragma unroll
    for (int r = 0; r < 16; ++r) {
        int row = (r & 3) + 8 * (r >> 2) + 4 * lq;
        op[(size_t)(m0 + row) * N + n]      = accM0[r] + accL0[r] * (1.f / 4096.f) + bv;
        op[(size_t)(m0 + 32 + row) * N + n] = accM1[r] + accL1[r] * (1.f / 4096.f) + bv;
    }
}

// ---------------------------------------------------------------------------
// fp32 GEMM for inp = x @ w_in^T + b_in (once, K=64); writes packed cur
// ---------------------------------------------------------------------------
#define GBK 16
#define GPAD 68
__global__ __launch_bounds__(256) void gemm_in(const float* __restrict__ x,
                                               const float* __restrict__ w_in,
                                               const float* __restrict__ b_in) {
    __shared__ __align__(16) float As[GBK][GPAD];
    __shared__ __align__(16) float Bs[GBK][GPAD];
    int tid = threadIdx.x;
    int tx = tid & 15, ty = tid >> 4;
    int m0 = blockIdx.y * 64, n0 = blockIdx.x * 64;
    int lm = tid >> 2, lk = (tid & 3) << 2;
    const int K = 64;
    float acc[4][4] = {};
    for (int k0 = 0; k0 < K; k0 += GBK) {
        float4 av = *(const float4*)(x + (size_t)(m0 + lm) * K + k0 + lk);
        float4 wv = *(const float4*)(w_in + (size_t)(n0 + lm) * K + k0 + lk);
        As[lk + 0][lm] = av.x; As[lk + 1][lm] = av.y;
        As[lk + 2][lm] = av.z; As[lk + 3][lm] = av.w;
        Bs[lk + 0][lm] = wv.x; Bs[lk + 1][lm] = wv.y;
        Bs[lk + 2][lm] = wv.z; Bs[lk + 3][lm] = wv.w;
        __syncthreads();
        #pragma unroll
        for (int kk = 0; kk < GBK; ++kk) {
            float4 a  = *(const float4*)&As[kk][ty * 4];
            float4 bq = *(const float4*)&Bs[kk][tx * 4];
            float aa[4] = {a.x, a.y, a.z, a.w};
            float bb[4] = {bq.x, bq.y, bq.z, bq.w};
            #pragma unroll
            for (int i = 0; i < 4; ++i)
                #pragma unroll
                for (int j = 0; j < 4; ++j)
                    acc[i][j] = fmaf(aa[i], bb[j], acc[i][j]);
        }
        __syncthreads();
    }
    #pragma unroll
    for (int i = 0; i < 4; ++i) {
        int m = m0 + ty * 4 + i;
        int n = n0 + tx * 4;
        half4v h, lo;
        #pragma unroll
        for (int j = 0; j < 4; ++j) {
            float v = acc[i][j] + b_in[n + j];
            _Float16 hv = (_Float16)v;
            h[j] = hv;
            lo[j] = (_Float16)((v - (float)hv) * 4096.f);
        }
        size_t po = packoff(m, n, EDIM);
        *(half4v*)&g_curh[po] = h;
        *(half4v*)&g_curl[po] = lo;
    }
}

__device__ __forceinline__ float sigm(float x) { return 1.f / (1.f + expf(-x)); }

// ---------------------------------------------------------------------------
// LSTM cell 0: gates = part0+part1+bsum0 -> h0 (packed K=1024), c0.
// ---------------------------------------------------------------------------
__global__ void lstm0_kernel() {
    int qidx = blockIdx.x * 256 + threadIdx.x;
    int b = qidx >> 8;
    int j = (qidx & 255) * 4;
    size_t base = (size_t)b * 4096;
    float4 G[4];
    #pragma unroll
    for (int g = 0; g < 4; ++g) {
        float4 p0 = *(const float4*)&g_part_g[base + g * 1024 + j];
        float4 p1 = *(const float4*)&g_part_g[PGS + base + g * 1024 + j];
        float4 bs = *(const float4*)&g_bsum0[g * 1024 + j];
        G[g].x = p0.x + p1.x + bs.x;
        G[g].y = p0.y + p1.y + bs.y;
        G[g].z = p0.z + p1.z + bs.z;
        G[g].w = p0.w + p1.w + bs.w;
    }
    size_t hb = (size_t)b * HDIM + j;
    float4 cin = *(const float4*)&g_c0[hb];
    float ci[4] = {cin.x, cin.y, cin.z, cin.w};
    float gi[4] = {G[0].x, G[0].y, G[0].z, G[0].w};
    float gf[4] = {G[1].x, G[1].y, G[1].z, G[1].w};
    float gg[4] = {G[2].x, G[2].y, G[2].z, G[2].w};
    float go[4] = {G[3].x, G[3].y, G[3].z, G[3].w};
    float c[4], h[4];
    half4v hh, hl;
    #pragma unroll
    for (int r = 0; r < 4; ++r) {
        c[r] = sigm(gf[r]) * ci[r] + sigm(gi[r]) * tanhf(gg[r]);
        h[r] = sigm(go[r]) * tanhf(c[r]);
        _Float16 hi16 = (_Float16)h[r];
        hh[r] = hi16;
        hl[r] = (_Float16)((h[r] - (float)hi16) * 4096.f);
    }
    *(float4*)&g_c0[hb] = {c[0], c[1], c[2], c[3]};
    size_t po = packoff(b, j, HDIM);
    *(half4v*)&g_h0h[po] = hh;
    *(half4v*)&g_h0l[po] = hl;
}

// ---------------------------------------------------------------------------
// LSTM cell 1 + LayerNorm: one block per row; writes packed h1, hn.
// ---------------------------------------------------------------------------
__global__ __launch_bounds__(256) void lstm1_ln_kernel(
    const float* __restrict__ ln_g, const float* __restrict__ ln_b)
{
    __shared__ float sbuf[4];
    int b = blockIdx.x, tid = threadIdx.x;
    int lane = tid & 63, wid = tid >> 6;
    int j = tid * 4;
    size_t base = (size_t)b * 4096;
    float4 G[4];
    #pragma unroll
    for (int g = 0; g < 4; ++g) {
        float4 p0 = *(const float4*)&g_part_g[base + g * 1024 + j];
        float4 p1 = *(const float4*)&g_part_g[PGS + base + g * 1024 + j];
        float4 bs = *(const float4*)&g_bsum1[g * 1024 + j];
        G[g].x = p0.x + p1.x + bs.x;
        G[g].y = p0.y + p1.y + bs.y;
        G[g].z = p0.z + p1.z + bs.z;
        G[g].w = p0.w + p1.w + bs.w;
    }
    size_t hb = (size_t)b * HDIM + j;
    float4 cin = *(const float4*)&g_c1[hb];
    float ci[4] = {cin.x, cin.y, cin.z, cin.w};
    float gi[4] = {G[0].x, G[0].y, G[0].z, G[0].w};
    float gf[4] = {G[1].x, G[1].y, G[1].z, G[1].w};
    float gg[4] = {G[2].x, G[2].y, G[2].z, G[2].w};
    float go[4] = {G[3].x, G[3].y, G[3].z, G[3].w};
    float c[4], h[4];
    float sum = 0.f;
    #pragma unroll
    for (int r = 0; r < 4; ++r) {
        c[r] = sigm(gf[r]) * ci[r] + sigm(gi[r]) * tanhf(gg[r]);
        h[r] = sigm(go[r]) * tanhf(c[r]);
        sum += h[r];
    }
    *(float4*)&g_c1[hb] = {c[0], c[1], c[2], c[3]};
    size_t po = packoff(b, j, HDIM);
    half4v h1h, h1l;
    #pragma unroll
    for (int r = 0; r < 4; ++r) {
        _Float16 hi16 = (_Float16)h[r];
        h1h[r] = hi16;
        h1l[r] = (_Float16)((h[r] - (float)hi16) * 4096.f);
    }
    *(half4v*)&g_h1h[po] = h1h;
    *(half4v*)&g_h1l[po] = h1l;

    for (int off = 32; off > 0; off >>= 1) sum += __shfl_down(sum, off, 64);
    if (lane == 0) sbuf[wid] = sum;
    __syncthreads();
    float mu = (sbuf[0] + sbuf[1] + sbuf[2] + sbuf[3]) * (1.f / HDIM);
    __syncthreads();
    float sq = 0.f;
    #pragma unroll
    for (int r = 0; r < 4; ++r) { float d = h[r] - mu; sq += d * d; }
    for (int off = 32; off > 0; off >>= 1) sq += __shfl_down(sq, off, 64);
    if (lane == 0) sbuf[wid] = sq;
    __syncthreads();
    float var = (sbuf[0] + sbuf[1] + sbuf[2] + sbuf[3]) * (1.f / HDIM);
    float rstd = 1.f / sqrtf(var + 1e-5f);
    half4v nh, nl;
    #pragma unroll
    for (int r = 0; r < 4; ++r) {
        float hn = (h[r] - mu) * rstd * ln_g[j + r] + ln_b[j + r];
        _Float16 hi16 = (_Float16)hn;
        nh[r] = hi16;
        nl[r] = (_Float16)((hn - (float)hi16) * 4096.f);
    }
    *(half4v*)&g_hnh[po] = nh;
    *(half4v*)&g_hnl[po] = nl;
}

// ---------------------------------------------------------------------------
// per-row softmax over logits = sum of 8 partials + b_out; writes packed cur
// ---------------------------------------------------------------------------
__global__ __launch_bounds__(256) void softmax_row_kernel(
    const float* __restrict__ b_out, const float* __restrict__ emb,
    float* __restrict__ out, int t)
{
    __shared__ float swv[4];
    __shared__ int   swi[4];
    __shared__ float sZ[4], sS[4];
    __shared__ float s_max;
    __shared__ int   s_idx;
    int b = blockIdx.x, tid = threadIdx.x;
    int lane = tid & 63, wid = tid >> 6;
    size_t base = (size_t)b * VDIM + 4 * tid;
    float4 xv = *(const float4*)&b_out[4 * tid];
    #pragma unroll
    for (int s = 0; s < 8; ++s) {
        float4 p = *(const float4*)&g_part_lg[(size_t)s * PLS + base];
        xv.x += p.x; xv.y += p.y; xv.z += p.z; xv.w += p.w;
    }

    float mv = xv.x; int mi = 4 * tid;
    if (xv.y > mv) { mv = xv.y; mi = 4 * tid + 1; }
    if (xv.z > mv) { mv = xv.z; mi = 4 * tid + 2; }
    if (xv.w > mv) { mv = xv.w; mi = 4 * tid + 3; }
    for (int off = 32; off > 0; off >>= 1) {
        float ov = __shfl_down(mv, off, 64);
        int   oi = __shfl_down(mi, off, 64);
        if (ov > mv || (ov == mv && oi < mi)) { mv = ov; mi = oi; }
    }
    if (lane == 0) { swv[wid] = mv; swi[wid] = mi; }
    __syncthreads();
    if (tid == 0) {
        mv = swv[0]; mi = swi[0];
        for (int w = 1; w < 4; ++w)
            if (swv[w] > mv || (swv[w] == mv && swi[w] < mi)) { mv = swv[w]; mi = swi[w]; }
        s_max = mv; s_idx = mi;
    }
    __syncthreads();
    float xmax = s_max;

    float sv[4] = {xv.x - xmax, xv.y - xmax, xv.z - xmax, xv.w - xmax};
    float z = 0.f, s1 = 0.f;
    #pragma unroll
    for (int r = 0; r < 4; ++r) { float e = expf(sv[r]); z += e; s1 += e * sv[r]; }
    for (int off = 32; off > 0; off >>= 1) {
        z  += __shfl_down(z, off, 64);
        s1 += __shfl_down(s1, off, 64);
    }
    if (lane == 0) { sZ[wid] = z; sS[wid] = s1; }
    __syncthreads();
    if (tid == 0) {
        float Z = sZ[0] + sZ[1] + sZ[2] + sZ[3];
        float S1 = sS[0] + sS[1] + sS[2] + sS[3];
        float logZ = logf(Z);
        float ent = logZ - S1 / Z;
        out[(size_t)b * TOUT + t]                         = (float)s_idx;
        out[(size_t)BQ * TOUT + (size_t)b * TOUT + t]     = -logZ;
        out[(size_t)2 * BQ * TOUT + (size_t)b * TOUT + t] = ent;
    }
    __syncthreads();
    int sym = s_idx;
    const float* e = emb + (size_t)sym * EDIM;
    for (int j = tid; j < EDIM; j += 256) {
        size_t po = packoff(b, j, EDIM);
        split1(e[j], &g_curh[po], &g_curl[po]);
    }
}

// ---------------------------------------------------------------------------
extern "C" void kernel_launch(void* const* d_in, const int* in_sizes, int n_in,
                              void* d_out, int out_size, void* d_ws, size_t ws_size,
                              hipStream_t stream) {
    const float* x     = (const float*)d_in[0];
    const float* w_in  = (const float*)d_in[1];
    const float* b_in  = (const float*)d_in[2];
    const float* w_ih0 = (const float*)d_in[3];
    const float* w_hh0 = (const float*)d_in[4];
    const float* b_ih0 = (const float*)d_in[5];
    const float* b_hh0 = (const float*)d_in[6];
    const float* w_ih1 = (const float*)d_in[7];
    const float* w_hh1 = (const float*)d_in[8];
    const float* b_ih1 = (const float*)d_in[9];
    const float* b_hh1 = (const float*)d_in[10];
    const float* ln_g  = (const float*)d_in[11];
    const float* ln_b  = (const float*)d_in[12];
    const float* w_out = (const float*)d_in[13];
    const float* b_out = (const float*)d_in[14];
    const float* emb   = (const float*)d_in[15];
    float* out = (float*)d_out;

    _Float16 *wih0h, *wih0l, *whh0h, *whh0l, *wih1h, *wih1l, *whh1h, *whh1l, *wouth, *woutl;
    hipGetSymbolAddress((void**)&wih0h, HIP_SYMBOL(g_wih0h));
    hipGetSymbolAddress((void**)&wih0l, HIP_SYMBOL(g_wih0l));
    hipGetSymbolAddress((void**)&whh0h, HIP_SYMBOL(g_whh0h));
    hipGetSymbolAddress((void**)&whh0l, HIP_SYMBOL(g_whh0l));
    hipGetSymbolAddress((void**)&wih1h, HIP_SYMBOL(g_wih1h));
    hipGetSymbolAddress((void**)&wih1l, HIP_SYMBOL(g_wih1l));
    hipGetSymbolAddress((void**)&whh1h, HIP_SYMBOL(g_whh1h));
    hipGetSymbolAddress((void**)&whh1l, HIP_SYMBOL(g_whh1l));
    hipGetSymbolAddress((void**)&wouth, HIP_SYMBOL(g_wouth));
    hipGetSymbolAddress((void**)&woutl, HIP_SYMBOL(g_woutl));
    _Float16 *curh, *curl, *h0h, *h0l, *h1h, *h1l, *hnh, *hnl;
    hipGetSymbolAddress((void**)&curh, HIP_SYMBOL(g_curh));
    hipGetSymbolAddress((void**)&curl, HIP_SYMBOL(g_curl));
    hipGetSymbolAddress((void**)&h0h, HIP_SYMBOL(g_h0h));
    hipGetSymbolAddress((void**)&h0l, HIP_SYMBOL(g_h0l));
    hipGetSymbolAddress((void**)&h1h, HIP_SYMBOL(g_h1h));
    hipGetSymbolAddress((void**)&h1l, HIP_SYMBOL(g_h1l));
    hipGetSymbolAddress((void**)&hnh, HIP_SYMBOL(g_hnh));
    hipGetSymbolAddress((void**)&hnl, HIP_SYMBOL(g_hnl));
    float *part_g, *part_lg;
    hipGetSymbolAddress((void**)&part_g, HIP_SYMBOL(g_part_g));
    hipGetSymbolAddress((void**)&part_lg, HIP_SYMBOL(g_part_lg));

    init_kernel<<<(BQ * HDIM) / 256, 256, 0, stream>>>(out, b_ih0, b_hh0, b_ih1, b_hh1);

    // one-time weight split+pack (klog = log2 K)
    split_pack_kernel<<<(4*HDIM*EDIM/4 + 255)/256, 256, 0, stream>>>(w_ih0, wih0h, wih0l, 9,  4*HDIM*EDIM/4);
    split_pack_kernel<<<(4*HDIM*HDIM/4 + 255)/256, 256, 0, stream>>>(w_hh0, whh0h, whh0l, 10, 4*HDIM*HDIM/4);
    split_pack_kernel<<<(4*HDIM*HDIM/4 + 255)/256, 256, 0, stream>>>(w_ih1, wih1h, wih1l, 10, 4*HDIM*HDIM/4);
    split_pack_kernel<<<(4*HDIM*HDIM/4 + 255)/256, 256, 0, stream>>>(w_hh1, whh1h, whh1l, 10, 4*HDIM*HDIM/4);
    split_pack_kernel<<<(VDIM*HDIM/4 + 255)/256, 256, 0, stream>>>(w_out, wouth, woutl, 10, VDIM*HDIM/4);

    gemm_in<<<dim3(EDIM / 64, BQ / 64), 256, 0, stream>>>(x, w_in, b_in);

    for (int t = 0; t < TLEN; ++t) {
        // gates0 = cur @ w_ih0^T + h0 @ w_hh0^T   (S=2 -> part_g; nt=32, NTP=4)
        gemm_big<<<256, 512, 0, stream>>>(
            curh, curl, EDIM, wih0h, wih0l,
            h0h, h0l, HDIM, whh0h, whh0l,
            (const float*)nullptr, part_g, 4 * HDIM, 2, 4);
        lstm0_kernel<<<(BQ * HDIM / 4) / 256, 256, 0, stream>>>();

        // gates1 = h0 @ w_ih1^T + h1 @ w_hh1^T   (S=2 -> part_g; NTP=4)
        gemm_big<<<256, 512, 0, stream>>>(
            h0h, h0l, HDIM, wih1h, wih1l,
            h1h, h1l, HDIM, whh1h, whh1l,
            (const float*)nullptr, part_g, 4 * HDIM, 2, 4);
        lstm1_ln_kernel<<<BQ, 256, 0, stream>>>(ln_g, ln_b);

        // logits partials = hn @ w_out^T   (S=8 -> 8 planes; nt=8, NTP=1)
        gemm_big<<<256, 512, 0, stream>>>(
            hnh, hnl, HDIM, wouth, woutl,
            (const _Float16*)nullptr, (const _Float16*)nullptr, 0,
            (const _Float16*)nullptr, (const _Float16*)nullptr,
            (const float*)nullptr, part_lg, VDIM, 8, 1);

        softmax_row_kernel<<<BQ, 256, 0, stream>>>(b_out, emb, out, t);
    }
}